// Round 2
// baseline (131.605 us; speedup 1.0000x reference)
//
#include <hip/hip_runtime.h>
#include <math.h>

#define Bn 4
#define Tn 2048
#define Dn 128
#define TDn 384
#define Cn 32
#define NCn 64            // chunks per batch = Tn/Cn
#define NCHUNK (Bn*NCn)   // 256 chunks total
#define NROW (Bn*Tn)      // 8192 rows

// ---------------------------------------------------------------------------
// Kernel T: Wt[k][c] = W[c][k]   (384x128 -> 128x384), 32x32 LDS tiles
// grid 48 (12 c-tiles x 4 k-tiles) x 256 threads
// ---------------------------------------------------------------------------
__global__ __launch_bounds__(256) void wt_kernel(
    const float* __restrict__ W, float* __restrict__ Wt)
{
    __shared__ float t[32][33];
    const int bi = blockIdx.x >> 2;      // c-tile 0..11
    const int bj = blockIdx.x & 3;       // k-tile 0..3
    const int r0 = bi * 32, c0 = bj * 32;
    const int tr = threadIdx.x >> 5, tc = threadIdx.x & 31;  // 8 x 32
#pragma unroll
    for (int rr = tr; rr < 32; rr += 8)
        t[rr][tc] = W[(r0 + rr) * 128 + c0 + tc];
    __syncthreads();
#pragma unroll
    for (int rr = tr; rr < 32; rr += 8)
        Wt[(c0 + rr) * 384 + r0 + tc] = t[tc][rr];
}

// ---------------------------------------------------------------------------
// Kernel A: qkv = x @ W^T + b ; q,k <- elu+1 ; split into q,k,v buffers
// grid 512 x 192; 16 rows/block; thread: cols (tid, tid+192) x 16 rows
// W consumed via Wt (k-major) -> lanes-consecutive coalesced global reads
// ---------------------------------------------------------------------------
__global__ __launch_bounds__(192) void qkv_kernel(
    const float* __restrict__ x, const float* __restrict__ Wt,
    const float* __restrict__ bias, float* __restrict__ qb,
    float* __restrict__ kb, float* __restrict__ vb)
{
    __shared__ __align__(16) float xs[16 * 128];
    const int tid = threadIdx.x;
    const int row0 = blockIdx.x * 16;

    {
        const float4* xg = (const float4*)(x + (size_t)row0 * 128);
        float4* xls = (float4*)xs;
        for (int i = tid; i < 16 * 32; i += 192) xls[i] = xg[i];
    }
    __syncthreads();

    const int c0 = tid, c1 = tid + 192;
    float acc0[16], acc1[16];
#pragma unroll
    for (int r = 0; r < 16; ++r) { acc0[r] = 0.f; acc1[r] = 0.f; }

    for (int k4 = 0; k4 < 32; ++k4) {
        float w0[4], w1[4];
#pragma unroll
        for (int u = 0; u < 4; ++u) {
            w0[u] = Wt[(size_t)(k4 * 4 + u) * 384 + c0];
            w1[u] = Wt[(size_t)(k4 * 4 + u) * 384 + c1];
        }
        float4 xv[16];
#pragma unroll
        for (int r = 0; r < 16; ++r) xv[r] = *(const float4*)&xs[r * 128 + k4 * 4];
#pragma unroll
        for (int r = 0; r < 16; ++r) {
            acc0[r] += xv[r].x * w0[0] + xv[r].y * w0[1] + xv[r].z * w0[2] + xv[r].w * w0[3];
            acc1[r] += xv[r].x * w1[0] + xv[r].y * w1[1] + xv[r].z * w1[2] + xv[r].w * w1[3];
        }
    }

    const float bb0 = bias[c0], bb1 = bias[c1];
#pragma unroll
    for (int r = 0; r < 16; ++r) {
        const size_t row = (size_t)(row0 + r);
        float v0 = acc0[r] + bb0;
        float v1 = acc1[r] + bb1;
        if (c0 < 128) qb[row * 128 + c0] = (v0 > 0.f) ? v0 + 1.f : expf(v0);
        else          kb[row * 128 + (c0 - 128)] = (v0 > 0.f) ? v0 + 1.f : expf(v0);
        if (c1 < 256) kb[row * 128 + (c1 - 128)] = (v1 > 0.f) ? v1 + 1.f : expf(v1);
        else          vb[row * 128 + (c1 - 256)] = v1;
    }
}

// ---------------------------------------------------------------------------
// Kernel B: per chunk (32 rows): S_local = K^T V (128x128), ksum = colsum(K)
// grid 256 x 256; 8x8 register tile per thread
// ---------------------------------------------------------------------------
__global__ __launch_bounds__(256) void chunkkv_kernel(
    const float* __restrict__ kb, const float* __restrict__ vb,
    float* __restrict__ kvb, float* __restrict__ ksb)
{
    __shared__ __align__(16) float sK[32 * 132];
    __shared__ __align__(16) float sV[32 * 132];
    const int tid = threadIdx.x;
    const int cb = blockIdx.x;
    const size_t base4 = (size_t)cb * (Cn * 128 / 4);

    {
        const float4* kg = (const float4*)kb + base4;
        const float4* vg = (const float4*)vb + base4;
        for (int i4 = tid; i4 < 32 * 32; i4 += 256) {
            int r = i4 >> 5, c4 = i4 & 31;
            ((float4*)&sK[r * 132])[c4] = kg[i4];
            ((float4*)&sV[r * 132])[c4] = vg[i4];
        }
    }
    __syncthreads();

    const int ty = tid >> 4, tx = tid & 15;
    const int i0 = ty * 8, j0 = tx * 8;
    float acc[8][8];
#pragma unroll
    for (int a = 0; a < 8; ++a)
#pragma unroll
        for (int b2 = 0; b2 < 8; ++b2) acc[a][b2] = 0.f;

#pragma unroll 2
    for (int t = 0; t < 32; ++t) {
        float4 ka = *(const float4*)&sK[t * 132 + i0];
        float4 kb4 = *(const float4*)&sK[t * 132 + i0 + 4];
        float4 va = *(const float4*)&sV[t * 132 + j0];
        float4 vb4 = *(const float4*)&sV[t * 132 + j0 + 4];
        float kk[8] = {ka.x, ka.y, ka.z, ka.w, kb4.x, kb4.y, kb4.z, kb4.w};
        float vv[8] = {va.x, va.y, va.z, va.w, vb4.x, vb4.y, vb4.z, vb4.w};
#pragma unroll
        for (int a = 0; a < 8; ++a)
#pragma unroll
            for (int b2 = 0; b2 < 8; ++b2) acc[a][b2] += kk[a] * vv[b2];
    }

    float* outp = kvb + (size_t)cb * 16384;
#pragma unroll
    for (int a = 0; a < 8; ++a) {
        *(float4*)&outp[(i0 + a) * 128 + j0] =
            make_float4(acc[a][0], acc[a][1], acc[a][2], acc[a][3]);
        *(float4*)&outp[(i0 + a) * 128 + j0 + 4] =
            make_float4(acc[a][4], acc[a][5], acc[a][6], acc[a][7]);
    }

    if (tid < 128) {
        float s = 0.f;
#pragma unroll
        for (int t = 0; t < 32; ++t) s += sK[t * 132 + tid];
        ksb[cb * 128 + tid] = s;
    }
}

// ---------------------------------------------------------------------------
// Kernel C: in-place exclusive prefix over 64 chunks per batch.
// Scalar lines -> 65536 kv lines + 512 ks lines -> 258 blocks (all CUs busy).
// 16-deep load batching keeps >=16 loads in flight per thread.
// ---------------------------------------------------------------------------
__global__ __launch_bounds__(256) void prefix_kernel(
    float* __restrict__ kvb, float* __restrict__ ksb)
{
    const int tid = threadIdx.x;
    if (blockIdx.x < 256) {
        const int L = blockIdx.x * 256 + tid;      // 0..65535 : (b, ij)
        const int b = L >> 14, ij = L & 16383;
        float* p = kvb + (size_t)b * NCn * 16384 + ij;
        float run = 0.f;
        for (int g = 0; g < 4; ++g) {
            float buf[16];
#pragma unroll
            for (int j = 0; j < 16; ++j) buf[j] = p[(size_t)(g * 16 + j) * 16384];
#pragma unroll
            for (int j = 0; j < 16; ++j) {
                p[(size_t)(g * 16 + j) * 16384] = run;
                run += buf[j];
            }
        }
    } else {
        const int L = (blockIdx.x - 256) * 256 + tid;  // 0..511 : (b, i)
        const int b = L >> 7, i = L & 127;
        float* p = ksb + (size_t)b * NCn * 128 + i;
        float run = 0.f;
        for (int g = 0; g < 4; ++g) {
            float buf[16];
#pragma unroll
            for (int j = 0; j < 16; ++j) buf[j] = p[(size_t)(g * 16 + j) * 128];
#pragma unroll
            for (int j = 0; j < 16; ++j) {
                p[(size_t)(g * 16 + j) * 128] = run;
                run += buf[j];
            }
        }
    }
}

// ---------------------------------------------------------------------------
// Kernel D: per chunk: out = (Q @ S_prefix + causal(QK^T) @ V) / den
// den[t] = Q[t].kpre + rowsum(masked scores[t]) + 1e-6
// grid 256 x 512 threads (8 waves -> 2/SIMD); LDS ~123 KB (1 block/CU)
// thread = 1 row (ty=tid>>4) x 8 cols (j0 = (tid&15)*8); mask at score-write
// ---------------------------------------------------------------------------
__global__ __launch_bounds__(512) void out_kernel(
    const float* __restrict__ qb, const float* __restrict__ kb,
    const float* __restrict__ vb, const float* __restrict__ kvb,
    const float* __restrict__ ksb, float* __restrict__ out)
{
    __shared__ __align__(16) float sS[128 * 132];
    __shared__ __align__(16) float sQ[32 * 132];
    __shared__ __align__(16) float sK[32 * 132];
    __shared__ __align__(16) float sV[32 * 132];
    __shared__ __align__(16) float sKp[128];
    __shared__ __align__(16) float sSc[32 * 33];
    __shared__ __align__(16) float sDen[32];

    const int tid = threadIdx.x;
    const int cb = blockIdx.x;
    const size_t base4 = (size_t)cb * (Cn * 128 / 4);

    {
        const float4* gS = (const float4*)(kvb + (size_t)cb * 16384);
        for (int i4 = tid; i4 < 128 * 32; i4 += 512) {
            int r = i4 >> 5, c4 = i4 & 31;
            ((float4*)&sS[r * 132])[c4] = gS[i4];
        }
        const float4* qg = (const float4*)qb + base4;
        const float4* kg = (const float4*)kb + base4;
        const float4* vg = (const float4*)vb + base4;
        for (int i4 = tid; i4 < 32 * 32; i4 += 512) {
            int r = i4 >> 5, c4 = i4 & 31;
            ((float4*)&sQ[r * 132])[c4] = qg[i4];
            ((float4*)&sK[r * 132])[c4] = kg[i4];
            ((float4*)&sV[r * 132])[c4] = vg[i4];
        }
        if (tid < 128) sKp[tid] = ksb[cb * 128 + tid];
    }
    __syncthreads();

    // scores[t][tp] = (tp<=t) ? Q[t].K[tp] : 0   (2 per thread)
    for (int s = tid; s < 1024; s += 512) {
        const int t = s >> 5, tp = s & 31;
        float d = 0.f;
#pragma unroll
        for (int k4 = 0; k4 < 32; ++k4) {
            float4 a = *(const float4*)&sQ[t * 132 + k4 * 4];
            float4 b2 = *(const float4*)&sK[tp * 132 + k4 * 4];
            d += a.x * b2.x + a.y * b2.y + a.z * b2.z + a.w * b2.w;
        }
        sSc[t * 33 + tp] = (tp <= t) ? d : 0.f;
    }
    __syncthreads();

    // den (32 threads; masked zeros make the rowsum uniform)
    if (tid < 32) {
        const int t = tid;
        float d = 0.f;
#pragma unroll
        for (int k4 = 0; k4 < 32; ++k4) {
            float4 a = *(const float4*)&sQ[t * 132 + k4 * 4];
            float4 b2 = *(const float4*)&sKp[k4 * 4];
            d += a.x * b2.x + a.y * b2.y + a.z * b2.z + a.w * b2.w;
        }
#pragma unroll
        for (int tp = 0; tp < 32; ++tp) d += sSc[t * 33 + tp];
        sDen[t] = d + 1e-6f;
    }

    const int ty = tid >> 4, tx = tid & 15;
    const int j0 = tx * 8;
    float acc[8];
#pragma unroll
    for (int c = 0; c < 8; ++c) acc[c] = 0.f;

    // inter: acc[j] += sum_i Q[ty][i] * S[i][j]
    for (int i = 0; i < 128; ++i) {
        const float q0 = sQ[ty * 132 + i];
        float4 sA = *(const float4*)&sS[i * 132 + j0];
        float4 sB = *(const float4*)&sS[i * 132 + j0 + 4];
        acc[0] += q0 * sA.x; acc[1] += q0 * sA.y; acc[2] += q0 * sA.z; acc[3] += q0 * sA.w;
        acc[4] += q0 * sB.x; acc[5] += q0 * sB.y; acc[6] += q0 * sB.z; acc[7] += q0 * sB.w;
    }

    // intra: uniform 32-iteration loop (masked scores are zero)
#pragma unroll 2
    for (int tp = 0; tp < 32; ++tp) {
        const float s0 = sSc[ty * 33 + tp];
        float4 va = *(const float4*)&sV[tp * 132 + j0];
        float4 vb4 = *(const float4*)&sV[tp * 132 + j0 + 4];
        acc[0] += s0 * va.x; acc[1] += s0 * va.y; acc[2] += s0 * va.z; acc[3] += s0 * va.w;
        acc[4] += s0 * vb4.x; acc[5] += s0 * vb4.y; acc[6] += s0 * vb4.z; acc[7] += s0 * vb4.w;
    }
    __syncthreads();   // sDen visible

    const float den0 = sDen[ty];
    float* o0 = out + ((size_t)cb * Cn + ty) * 128 + j0;
    *(float4*)o0 = make_float4(acc[0] / den0, acc[1] / den0, acc[2] / den0, acc[3] / den0);
    *(float4*)(o0 + 4) = make_float4(acc[4] / den0, acc[5] / den0, acc[6] / den0, acc[7] / den0);
}

// ---------------------------------------------------------------------------
extern "C" void kernel_launch(void* const* d_in, const int* in_sizes, int n_in,
                              void* d_out, int out_size, void* d_ws, size_t ws_size,
                              hipStream_t stream)
{
    const float* x = (const float*)d_in[0];     // (B,T,D)
    const float* W = (const float*)d_in[1];     // (3D, D)
    const float* bias = (const float*)d_in[2];  // (3D,)
    float* out = (float*)d_out;                 // (B,T,D)

    float* ws = (float*)d_ws;
    float* qb = ws;                              // 1,048,576 floats
    float* kb = ws + 1048576;                    // 1,048,576
    float* vb = ws + 2097152;                    // 1,048,576
    float* kvb = ws + 3145728;                   // 4,194,304 (B*NC*D*D)
    float* ksb = ws + 3145728 + 4194304;         // 32,768    (B*NC*D)
    float* Wt  = ws + 3145728 + 4194304 + 32768; // 49,152    (128x384)

    wt_kernel<<<48, 256, 0, stream>>>(W, Wt);
    qkv_kernel<<<NROW / 16, 192, 0, stream>>>(x, Wt, bias, qb, kb, vb);
    chunkkv_kernel<<<NCHUNK, 256, 0, stream>>>(kb, vb, kvb, ksb);
    prefix_kernel<<<258, 256, 0, stream>>>(kvb, ksb);
    out_kernel<<<NCHUNK, 512, 0, stream>>>(qb, kb, vb, kvb, ksb, out);
}